// Round 7
// baseline (314.969 us; speedup 1.0000x reference)
//
#include <hip/hip_runtime.h>

#define NS 10000
#define DD 64
#define HH 128
#define EE 50000
#define SLOPE 0.01f
#define TPAD 132   // Ts row stride in shorts ([node*2+f][k], k=128 + 4 pad)

typedef __attribute__((ext_vector_type(8))) short short8;
typedef __attribute__((ext_vector_type(4))) unsigned short us4;
typedef __attribute__((ext_vector_type(4))) float f32x4;

static __device__ __forceinline__ unsigned short f2bf(float f) {
  unsigned int u = __float_as_uint(f);
  u += 0x7fff + ((u >> 16) & 1);   // round-to-nearest-even
  return (unsigned short)(u >> 16);
}
static __device__ __forceinline__ float bf2f(unsigned short s) {
  return __uint_as_float((unsigned int)s << 16);
}

__device__ __forceinline__ float wave_sum64(float v) {
  #pragma unroll
  for (int m = 32; m >= 1; m >>= 1) v += __shfl_xor(v, m, 64);
  return v;
}

// A: h = leaky(LN(x)) (+bf16), degree counts, ea->bf16, w2->w2t2 bf16.
// grid 2500x256 = 640k threads (>= 524288 for w2t2).
__global__ __launch_bounds__(256) void k_prep(const float* __restrict__ x,
    const float* __restrict__ gamma, const float* __restrict__ beta,
    float* __restrict__ h, unsigned short* __restrict__ hbf,
    const float* __restrict__ ea, unsigned short* __restrict__ eabf,
    const float* __restrict__ w2, unsigned short* __restrict__ w2t2,
    const int* __restrict__ ei, int* __restrict__ cntsrc,
    int* __restrict__ cntdst) {
  int gid = blockIdx.x * 256 + threadIdx.x;
  if (gid < EE) {
    atomicAdd(&cntsrc[ei[gid]], 1);
    atomicAdd(&cntdst[ei[EE + gid]], 1);
  }
  if (gid < EE * DD / 8) {
    const float4* sp = (const float4*)(ea + (size_t)gid * 8);
    float4 v0 = sp[0], v1 = sp[1];
    short8 o;
    o[0] = f2bf(v0.x); o[1] = f2bf(v0.y); o[2] = f2bf(v0.z); o[3] = f2bf(v0.w);
    o[4] = f2bf(v1.x); o[5] = f2bf(v1.y); o[6] = f2bf(v1.z); o[7] = f2bf(v1.w);
    *(short8*)(eabf + (size_t)gid * 8) = o;
  }
  if (gid < HH * DD * DD) {
    int d = gid & 63;
    int c2 = gid >> 6;
    int f = c2 >> 7, k = c2 & 127;
    w2t2[gid] = f2bf(w2[k * (DD * DD) + d * DD + f]);
  }
  int wid = threadIdx.x >> 6;
  int lane = threadIdx.x & 63;
  int row = blockIdx.x * 4 + wid;
  if (row >= NS) return;
  float v = x[row * DD + lane];
  float s = wave_sum64(v);
  float s2 = wave_sum64(v * v);
  float mu = s * (1.0f / 64.0f);
  float var = s2 * (1.0f / 64.0f) - mu * mu;
  float r = rsqrtf(var + 1e-5f);
  float hn = (v - mu) * r * gamma[lane] + beta[lane];
  float hv = hn >= 0.f ? hn : SLOPE * hn;
  h[row * DD + lane] = hv;
  hbf[row * DD + lane] = f2bf(hv);
}

// B: blocks [0,782): u = bf16(leaky(eabf@w1+b1)) via MFMA (64 rows/block);
//    blocks [782,1095): cc = h@b2 (32 rows/block);
//    block 1095: exclusive scan of cntsrc -> rowptr, cursor.
#define UBLK 782
#define GBLK 313
__global__ __launch_bounds__(256) void k_mid(
    const unsigned short* __restrict__ eabf, const float* __restrict__ w1,
    const float* __restrict__ b1, unsigned short* __restrict__ ubf,
    const float* __restrict__ h, const float* __restrict__ b2,
    float* __restrict__ cc, const int* __restrict__ cntsrc,
    int* __restrict__ rowptr, int* __restrict__ cursor) {
  __shared__ __align__(16) unsigned char smem[27648];
  int t = threadIdx.x;
  int bid = blockIdx.x;
  if (bid < UBLK) {
    unsigned short (*As)[72] = (unsigned short(*)[72])smem;
    unsigned short (*Bs)[72] = (unsigned short(*)[72])(smem + 9216);
    int row0 = bid * 64;
    #pragma unroll
    for (int i = 0; i < 2; ++i) {
      int idx = t + i * 256;
      int r = idx >> 3, c = (idx & 7) * 8;
      int gr = row0 + r;
      short8 v = {};
      if (gr < EE) v = *(const short8*)(eabf + (size_t)gr * DD + c);
      *(short8*)(&As[r][c]) = v;
    }
    #pragma unroll
    for (int i = 0; i < 32; ++i) {
      int idx = t + i * 256;          // 0..8191
      int hc = idx >> 6, d = idx & 63;
      Bs[hc][d] = f2bf(w1[d * HH + hc]);
    }
    __syncthreads();
    int w = t >> 6, lane = t & 63, lr = lane & 15, lg = lane >> 4;
    f32x4 acc[8] = {};
    #pragma unroll
    for (int kk = 0; kk < 64; kk += 32) {
      short8 a = *(const short8*)(&As[w * 16 + lr][kk + lg * 8]);
      #pragma unroll
      for (int ni = 0; ni < 8; ++ni) {
        short8 b = *(const short8*)(&Bs[ni * 16 + lr][kk + lg * 8]);
        acc[ni] = __builtin_amdgcn_mfma_f32_16x16x32_bf16(a, b, acc[ni], 0, 0, 0);
      }
    }
    #pragma unroll
    for (int ni = 0; ni < 8; ++ni) {
      int col = ni * 16 + lr;
      float bb = b1[col];
      #pragma unroll
      for (int r = 0; r < 4; ++r) {
        int gr = row0 + w * 16 + lg * 4 + r;
        if (gr < EE) {
          float vv = acc[ni][r] + bb;
          ubf[(size_t)gr * HH + col] = f2bf(vv >= 0.f ? vv : SLOPE * vv);
        }
      }
    }
  } else if (bid < UBLK + GBLK) {
    float (*Bsg)[65] = (float(*)[65])smem;            // 16640 B
    float (*Asg)[64] = (float(*)[64])(smem + 16640);  // 8192 B
    int row0 = (bid - UBLK) * 32;
    #pragma unroll
    for (int i = 0; i < 16; ++i) {
      int idx = t + i * 256;
      Bsg[idx >> 6][idx & 63] = b2[idx];
    }
    #pragma unroll
    for (int i = 0; i < 8; ++i) {
      int idx = t + i * 256;
      int r = idx >> 6, d = idx & 63;
      int gr = row0 + r;
      Asg[r][d] = (gr < NS) ? h[gr * DD + d] : 0.f;
    }
    __syncthreads();
    int r = t >> 3;
    int c0 = (t & 7) * 8;
    int gr = row0 + r;
    if (gr >= NS) return;
    float acc[8] = {};
    for (int d = 0; d < DD; ++d) {
      float a = Asg[r][d];
      #pragma unroll
      for (int j = 0; j < 8; ++j) acc[j] += a * Bsg[d][c0 + j];
    }
    #pragma unroll
    for (int j = 0; j < 8; ++j) cc[(size_t)gr * DD + c0 + j] = acc[j];
  } else {
    int* ps = (int*)smem;
    const int CH = (NS + 255) / 256;   // 40
    int base = t * CH;
    int sum = 0;
    for (int i = 0; i < CH; ++i) {
      int idx = base + i;
      if (idx < NS) sum += cntsrc[idx];
    }
    ps[t] = sum;
    __syncthreads();
    for (int off = 1; off < 256; off <<= 1) {
      int v = (t >= off) ? ps[t - off] : 0;
      __syncthreads();
      ps[t] += v;
      __syncthreads();
    }
    int run = ps[t] - sum;
    for (int i = 0; i < CH; ++i) {
      int idx = base + i;
      if (idx < NS) {
        rowptr[idx] = run;
        cursor[idx] = run;
        run += cntsrc[idx];
      }
    }
    if (t == 255) rowptr[NS] = run;
  }
}

__global__ __launch_bounds__(256) void k_scatter(const int* __restrict__ ei,
    int* __restrict__ cursor, int* __restrict__ eord) {
  int e = blockIdx.x * 256 + threadIdx.x;
  if (e < EE) {
    int s = ei[e];
    int pos = atomicAdd(&cursor[s], 1);
    eord[pos] = e;
  }
}

// Fused T+message, f-major chunks. Block (bx,by): 64 src nodes, f-range
// [by*8, by*8+8). 4 sub-chunks of (2 f x 128 k): MFMA 64x256 T-tile -> LDS
// (bf16), then apply: per edge dot(u[e,:], Ts[nl][f][:]) -> atomicAdd agg.
// T never touches HBM.
__global__ __launch_bounds__(256) void k_fused2(
    const unsigned short* __restrict__ hbf, const unsigned short* __restrict__ w2t2,
    const unsigned short* __restrict__ ubf, const float* __restrict__ cc,
    const int* __restrict__ ei, const int* __restrict__ rowptr,
    const int* __restrict__ eord, float* __restrict__ agg) {
  __shared__ unsigned short As[64][72];
  __shared__ unsigned short Ts[128 * TPAD];   // [node*2+f][k] 33.8 KB
  int t = threadIdx.x;
  int n0 = blockIdx.x * 64;
  int by = blockIdx.y;
  #pragma unroll
  for (int i = 0; i < 2; ++i) {
    int idx = t + i * 256;
    int r = idx >> 3, c = (idx & 7) * 8;
    int gr = n0 + r;
    short8 v = {};
    if (gr < NS) v = *(const short8*)(hbf + (size_t)gr * DD + c);
    *(short8*)(&As[r][c]) = v;
  }
  __syncthreads();
  int w = t >> 6, lane = t & 63, lr = lane & 15, lg = lane >> 4;
  short8 a2[4][2];
  #pragma unroll
  for (int mi = 0; mi < 4; ++mi)
    #pragma unroll
    for (int ks = 0; ks < 2; ++ks)
      a2[mi][ks] = *(const short8*)(&As[mi * 16 + lr][ks * 32 + lg * 8]);

  int nend = n0 + 64 < NS ? n0 + 64 : NS;
  int beg = rowptr[n0];
  int end = rowptr[nend];

  for (int sc = 0; sc < 4; ++sc) {
    int c0 = by * 1024 + sc * 256;
    // MFMA: 64 nodes x 256 c2-cols; B-frags straight from L2-resident w2t2.
    f32x4 acc[4][4] = {};
    #pragma unroll
    for (int ni = 0; ni < 4; ++ni) {
      int gc = c0 + w * 64 + ni * 16 + lr;
      const unsigned short* bp = w2t2 + (size_t)gc * DD;
      short8 b0 = *(const short8*)(bp + lg * 8);
      short8 b1 = *(const short8*)(bp + 32 + lg * 8);
      #pragma unroll
      for (int mi = 0; mi < 4; ++mi) {
        acc[mi][ni] = __builtin_amdgcn_mfma_f32_16x16x32_bf16(
            a2[mi][0], b0, acc[mi][ni], 0, 0, 0);
        acc[mi][ni] = __builtin_amdgcn_mfma_f32_16x16x32_bf16(
            a2[mi][1], b1, acc[mi][ni], 0, 0, 0);
      }
    }
    if (sc) __syncthreads();   // prior apply done before Ts overwrite
    #pragma unroll
    for (int mi = 0; mi < 4; ++mi)
      #pragma unroll
      for (int ni = 0; ni < 4; ++ni) {
        int c = w * 64 + ni * 16 + lr;
        int f = c >> 7, k = c & 127;
        int rowb = ((mi * 16 + lg * 4) * 2 + f) * TPAD + k;
        #pragma unroll
        for (int reg = 0; reg < 4; ++reg)
          Ts[rowb + reg * 2 * TPAD] = f2bf(acc[mi][ni][reg]);
      }
    __syncthreads();
    // apply: final msg contributions for f = fg, fg+1
    int fg = by * 8 + sc * 2;
    for (int j = beg + t; j < end; j += 256) {
      int e = eord[j];
      int nl = ei[e] - n0;
      int dst = ei[EE + e];
      const short8* up = (const short8*)(ubf + (size_t)e * HH);
      const unsigned short* t0 = &Ts[(nl * 2 + 0) * TPAD];
      const unsigned short* t1 = &Ts[(nl * 2 + 1) * TPAD];
      float s0 = 0.f, s1 = 0.f;
      #pragma unroll
      for (int kq = 0; kq < 16; ++kq) {
        short8 uv = up[kq];
        us4 p0a = *(const us4*)(t0 + kq * 8);
        us4 p0b = *(const us4*)(t0 + kq * 8 + 4);
        us4 p1a = *(const us4*)(t1 + kq * 8);
        us4 p1b = *(const us4*)(t1 + kq * 8 + 4);
        #pragma unroll
        for (int jj = 0; jj < 4; ++jj) {
          float uf = bf2f((unsigned short)uv[jj]);
          s0 = fmaf(uf, bf2f(p0a[jj]), s0);
          s1 = fmaf(uf, bf2f(p1a[jj]), s1);
        }
        #pragma unroll
        for (int jj = 0; jj < 4; ++jj) {
          float uf = bf2f((unsigned short)uv[4 + jj]);
          s0 = fmaf(uf, bf2f(p0b[jj]), s0);
          s1 = fmaf(uf, bf2f(p1b[jj]), s1);
        }
      }
      int sgl = n0 + nl;
      atomicAdd(&agg[(size_t)dst * DD + fg], s0 + cc[(size_t)sgl * DD + fg]);
      atomicAdd(&agg[(size_t)dst * DD + fg + 1],
                s1 + cc[(size_t)sgl * DD + fg + 1]);
    }
  }
}

// out = x + agg/max(cnt,1) + h@root + bias
__global__ __launch_bounds__(256) void k_final(const float* __restrict__ x,
    const float* __restrict__ h, const float* __restrict__ root,
    const float* __restrict__ bias, const float* __restrict__ agg,
    const int* __restrict__ cnt, float* __restrict__ out) {
  __shared__ float Bs[DD][DD + 1];
  __shared__ float As[32][DD];
  int t = threadIdx.x;
  #pragma unroll
  for (int i = 0; i < 16; ++i) {
    int idx = t + i * 256;
    Bs[idx >> 6][idx & 63] = root[idx];
  }
  int row0 = blockIdx.x * 32;
  #pragma unroll
  for (int i = 0; i < 8; ++i) {
    int idx = t + i * 256;
    int r = idx >> 6, d = idx & 63;
    int gr = row0 + r;
    As[r][d] = (gr < NS) ? h[gr * DD + d] : 0.f;
  }
  __syncthreads();
  int r = t >> 3;
  int c0 = (t & 7) * 8;
  int gr = row0 + r;
  if (gr >= NS) return;
  float acc[8] = {};
  for (int d = 0; d < DD; ++d) {
    float a = As[r][d];
    #pragma unroll
    for (int j = 0; j < 8; ++j) acc[j] += a * Bs[d][c0 + j];
  }
  float inv = 1.0f / fmaxf((float)cnt[gr], 1.0f);
  #pragma unroll
  for (int j = 0; j < 8; ++j) {
    size_t gi = (size_t)gr * DD + c0 + j;
    out[gi] = x[gi] + agg[gi] * inv + acc[j] + bias[c0 + j];
  }
}

extern "C" void kernel_launch(void* const* d_in, const int* in_sizes, int n_in,
                              void* d_out, int out_size, void* d_ws, size_t ws_size,
                              hipStream_t stream) {
  const float* x     = (const float*)d_in[0];
  const float* ea    = (const float*)d_in[1];
  const float* gamma = (const float*)d_in[2];
  const float* beta  = (const float*)d_in[3];
  const float* w1    = (const float*)d_in[4];
  const float* b1    = (const float*)d_in[5];
  const float* w2    = (const float*)d_in[6];
  const float* b2    = (const float*)d_in[7];
  const float* root  = (const float*)d_in[8];
  const float* bias  = (const float*)d_in[9];
  const int*   ei    = (const int*)d_in[10];
  float* out = (float*)d_out;

  char* p = (char*)d_ws;
  auto carve = [&](size_t bytes) {
    char* q = p;
    p += (bytes + 255) & ~(size_t)255;
    return q;
  };
  float* h             = (float*)carve(sizeof(float) * NS * DD);
  unsigned short* hbf  = (unsigned short*)carve(sizeof(short) * NS * DD);
  float* cc            = (float*)carve(sizeof(float) * NS * DD);
  unsigned short* w2t2 = (unsigned short*)carve(sizeof(short) * HH * DD * DD);
  unsigned short* eabf = (unsigned short*)carve(sizeof(short) * (size_t)EE * DD);
  unsigned short* ubf  = (unsigned short*)carve(sizeof(short) * (size_t)EE * HH);
  int* rowptr          = (int*)carve(sizeof(int) * (NS + 1));
  int* cursor          = (int*)carve(sizeof(int) * NS);
  int* eord            = (int*)carve(sizeof(int) * EE);
  // contiguous zero-region: agg | cntdst | cntsrc (single memset)
  char* z0 = p;
  float* agg           = (float*)carve(sizeof(float) * NS * DD);
  int* cntdst          = (int*)carve(sizeof(int) * NS);
  int* cntsrc          = (int*)carve(sizeof(int) * NS);
  size_t zlen = (size_t)(p - z0);

  hipMemsetAsync(z0, 0, zlen, stream);

  k_prep<<<dim3((NS + 3) / 4), dim3(256), 0, stream>>>(
      x, gamma, beta, h, hbf, ea, eabf, w2, w2t2, ei, cntsrc, cntdst);
  k_mid<<<dim3(UBLK + GBLK + 1), dim3(256), 0, stream>>>(
      eabf, w1, b1, ubf, h, b2, cc, cntsrc, rowptr, cursor);
  k_scatter<<<dim3((EE + 255) / 256), dim3(256), 0, stream>>>(ei, cursor, eord);
  k_fused2<<<dim3((NS + 63) / 64, 8), dim3(256), 0, stream>>>(
      hbf, w2t2, ubf, cc, ei, rowptr, eord, agg);
  k_final<<<dim3((NS + 31) / 32), dim3(256), 0, stream>>>(x, h, root, bias, agg,
                                                          cntdst, out);
}

// Round 8
// 190.768 us; speedup vs baseline: 1.6511x; 1.6511x over previous
//
#include <hip/hip_runtime.h>

#define NS 10000
#define DD 64
#define HH 128
#define EE 50000
#define SLOPE 0.01f
#define TSN 548   // Ts node stride (shorts): 16 f * 34 + 4 pad
#define TSF 34    // Ts f stride (shorts): 32 k + 2 pad

typedef __attribute__((ext_vector_type(8))) short short8;
typedef __attribute__((ext_vector_type(4))) float f32x4;

static __device__ __forceinline__ unsigned short f2bf(float f) {
  unsigned int u = __float_as_uint(f);
  u += 0x7fff + ((u >> 16) & 1);   // round-to-nearest-even
  return (unsigned short)(u >> 16);
}

__device__ __forceinline__ float wave_sum64(float v) {
  #pragma unroll
  for (int m = 32; m >= 1; m >>= 1) v += __shfl_xor(v, m, 64);
  return v;
}

// h = leaky(LN(x)) (+bf16), degree counts, ea->bf16, w2->w2t2 bf16.
__global__ __launch_bounds__(256) void k_prep(const float* __restrict__ x,
    const float* __restrict__ gamma, const float* __restrict__ beta,
    float* __restrict__ h, unsigned short* __restrict__ hbf,
    const float* __restrict__ ea, unsigned short* __restrict__ eabf,
    const float* __restrict__ w2, unsigned short* __restrict__ w2t2,
    const int* __restrict__ ei, int* __restrict__ cntsrc,
    int* __restrict__ cntdst) {
  int gid = blockIdx.x * 256 + threadIdx.x;
  if (gid < EE) {
    atomicAdd(&cntsrc[ei[gid]], 1);
    atomicAdd(&cntdst[ei[EE + gid]], 1);
  }
  if (gid < EE * DD / 8) {
    const float4* sp = (const float4*)(ea + (size_t)gid * 8);
    float4 v0 = sp[0], v1 = sp[1];
    short8 o;
    o[0] = f2bf(v0.x); o[1] = f2bf(v0.y); o[2] = f2bf(v0.z); o[3] = f2bf(v0.w);
    o[4] = f2bf(v1.x); o[5] = f2bf(v1.y); o[6] = f2bf(v1.z); o[7] = f2bf(v1.w);
    *(short8*)(eabf + (size_t)gid * 8) = o;
  }
  if (gid < HH * DD * DD) {
    int d = gid & 63;
    int c2 = gid >> 6;
    int f = c2 >> 7, k = c2 & 127;
    w2t2[gid] = f2bf(w2[k * (DD * DD) + d * DD + f]);
  }
  int wid = threadIdx.x >> 6;
  int lane = threadIdx.x & 63;
  int row = blockIdx.x * 4 + wid;
  if (row >= NS) return;
  float v = x[row * DD + lane];
  float s = wave_sum64(v);
  float s2 = wave_sum64(v * v);
  float mu = s * (1.0f / 64.0f);
  float var = s2 * (1.0f / 64.0f) - mu * mu;
  float r = rsqrtf(var + 1e-5f);
  float hn = (v - mu) * r * gamma[lane] + beta[lane];
  float hv = hn >= 0.f ? hn : SLOPE * hn;
  h[row * DD + lane] = hv;
  hbf[row * DD + lane] = f2bf(hv);
}

// blocks [0,782): ubf via MFMA; [782,1095): cc = h@b2; 1095: scan.
#define UBLK 782
#define GBLK 313
__global__ __launch_bounds__(256) void k_mid(
    const unsigned short* __restrict__ eabf, const float* __restrict__ w1,
    const float* __restrict__ b1, unsigned short* __restrict__ ubf,
    const float* __restrict__ h, const float* __restrict__ b2,
    float* __restrict__ cc, const int* __restrict__ cntsrc,
    int* __restrict__ rowptr, int* __restrict__ cursor) {
  __shared__ __align__(16) unsigned char smem[27648];
  int t = threadIdx.x;
  int bid = blockIdx.x;
  if (bid < UBLK) {
    unsigned short (*As)[72] = (unsigned short(*)[72])smem;
    unsigned short (*Bs)[72] = (unsigned short(*)[72])(smem + 9216);
    int row0 = bid * 64;
    #pragma unroll
    for (int i = 0; i < 2; ++i) {
      int idx = t + i * 256;
      int r = idx >> 3, c = (idx & 7) * 8;
      int gr = row0 + r;
      short8 v = {};
      if (gr < EE) v = *(const short8*)(eabf + (size_t)gr * DD + c);
      *(short8*)(&As[r][c]) = v;
    }
    #pragma unroll
    for (int i = 0; i < 32; ++i) {
      int idx = t + i * 256;
      int hc = idx >> 6, d = idx & 63;
      Bs[hc][d] = f2bf(w1[d * HH + hc]);
    }
    __syncthreads();
    int w = t >> 6, lane = t & 63, lr = lane & 15, lg = lane >> 4;
    f32x4 acc[8] = {};
    #pragma unroll
    for (int kk = 0; kk < 64; kk += 32) {
      short8 a = *(const short8*)(&As[w * 16 + lr][kk + lg * 8]);
      #pragma unroll
      for (int ni = 0; ni < 8; ++ni) {
        short8 b = *(const short8*)(&Bs[ni * 16 + lr][kk + lg * 8]);
        acc[ni] = __builtin_amdgcn_mfma_f32_16x16x32_bf16(a, b, acc[ni], 0, 0, 0);
      }
    }
    #pragma unroll
    for (int ni = 0; ni < 8; ++ni) {
      int col = ni * 16 + lr;
      float bb = b1[col];
      #pragma unroll
      for (int r = 0; r < 4; ++r) {
        int gr = row0 + w * 16 + lg * 4 + r;
        if (gr < EE) {
          float vv = acc[ni][r] + bb;
          ubf[(size_t)gr * HH + col] = f2bf(vv >= 0.f ? vv : SLOPE * vv);
        }
      }
    }
  } else if (bid < UBLK + GBLK) {
    float (*Bsg)[65] = (float(*)[65])smem;
    float (*Asg)[64] = (float(*)[64])(smem + 16640);
    int row0 = (bid - UBLK) * 32;
    #pragma unroll
    for (int i = 0; i < 16; ++i) {
      int idx = t + i * 256;
      Bsg[idx >> 6][idx & 63] = b2[idx];
    }
    #pragma unroll
    for (int i = 0; i < 8; ++i) {
      int idx = t + i * 256;
      int r = idx >> 6, d = idx & 63;
      int gr = row0 + r;
      Asg[r][d] = (gr < NS) ? h[gr * DD + d] : 0.f;
    }
    __syncthreads();
    int r = t >> 3;
    int c0 = (t & 7) * 8;
    int gr = row0 + r;
    if (gr >= NS) return;
    float acc[8] = {};
    for (int d = 0; d < DD; ++d) {
      float a = Asg[r][d];
      #pragma unroll
      for (int j = 0; j < 8; ++j) acc[j] += a * Bsg[d][c0 + j];
    }
    #pragma unroll
    for (int j = 0; j < 8; ++j) cc[(size_t)gr * DD + c0 + j] = acc[j];
  } else {
    int* ps = (int*)smem;
    const int CH = (NS + 255) / 256;
    int base = t * CH;
    int sum = 0;
    for (int i = 0; i < CH; ++i) {
      int idx = base + i;
      if (idx < NS) sum += cntsrc[idx];
    }
    ps[t] = sum;
    __syncthreads();
    for (int off = 1; off < 256; off <<= 1) {
      int v = (t >= off) ? ps[t - off] : 0;
      __syncthreads();
      ps[t] += v;
      __syncthreads();
    }
    int run = ps[t] - sum;
    for (int i = 0; i < CH; ++i) {
      int idx = base + i;
      if (idx < NS) {
        rowptr[idx] = run;
        cursor[idx] = run;
        run += cntsrc[idx];
      }
    }
    if (t == 255) rowptr[NS] = run;
  }
}

__global__ __launch_bounds__(256) void k_scatter(const int* __restrict__ ei,
    int* __restrict__ cursor, int* __restrict__ eord) {
  int e = blockIdx.x * 256 + threadIdx.x;
  if (e < EE) {
    int s = ei[e];
    int pos = atomicAdd(&cursor[s], 1);
    eord[pos] = e;
  }
}

// Fused producer+consumer, both MFMA. Block (bx,by): 32 src nodes, f-chunk
// [by*16, by*16+16), loop 4 k-quarters. Producer: T-quarter -> LDS Ts
// (k_T_mfma pattern). Consumer: k_msg_wave pattern, B-frags from Ts.
// T never touches HBM.
__global__ __launch_bounds__(256) void k_fused3(
    const unsigned short* __restrict__ hbf, const unsigned short* __restrict__ w2t2,
    const unsigned short* __restrict__ ubf, const float* __restrict__ cc,
    const int* __restrict__ ei, const int* __restrict__ rowptr,
    const int* __restrict__ eord, float* __restrict__ agg) {
  __shared__ unsigned short hs[32][72];
  __shared__ unsigned short Ts[32 * TSN];
  __shared__ float ccs[32][16];
  int t = threadIdx.x;
  int n0 = blockIdx.x * 32;
  int by = blockIdx.y;
  {
    int r = t >> 3, c = (t & 7) * 8;
    int n = n0 + r;
    short8 v = {};
    if (n < NS) v = *(const short8*)(hbf + (size_t)n * DD + c);
    *(short8*)(&hs[r][c]) = v;
  }
  #pragma unroll
  for (int i = 0; i < 2; ++i) {
    int idx = t + i * 256;
    int row = idx >> 4, f = idx & 15;
    int s = n0 + row;
    ccs[row][f] = (s < NS) ? cc[(size_t)s * DD + by * 16 + f] : 0.f;
  }
  int w = t >> 6, lane = t & 63, lr = lane & 15, lg = lane >> 4;
  __syncthreads();

  short8 a[2][2];
  #pragma unroll
  for (int mi = 0; mi < 2; ++mi)
    #pragma unroll
    for (int ks = 0; ks < 2; ++ks)
      a[mi][ks] = *(const short8*)(&hs[mi * 16 + lr][ks * 32 + lg * 8]);

  int beg8[8], deg8[8];
  #pragma unroll
  for (int i = 0; i < 8; ++i) {
    int s = n0 + w * 8 + i;
    int b = 0, d = 0;
    if (s < NS) { b = rowptr[s]; d = rowptr[s + 1] - b; }
    beg8[i] = b; deg8[i] = d;
  }
  f32x4 acc0[8] = {};

  for (int kq = 0; kq < 4; ++kq) {
    if (kq) __syncthreads();
    // ---- producer: wave w computes f-slice [4w,4w+4), 32 k, for 32 nodes.
    #pragma unroll
    for (int ni = 0; ni < 8; ++ni) {
      int floc = w * 4 + (ni >> 1);
      int k0 = (ni & 1) * 16;
      size_t c2 = (size_t)((by * 16 + floc) * 128 + kq * 32 + k0 + lr);
      const unsigned short* bp = w2t2 + c2 * DD;
      short8 b0 = *(const short8*)(bp + lg * 8);
      short8 b1 = *(const short8*)(bp + 32 + lg * 8);
      f32x4 c0 = {}, c1 = {};
      c0 = __builtin_amdgcn_mfma_f32_16x16x32_bf16(a[0][0], b0, c0, 0, 0, 0);
      c0 = __builtin_amdgcn_mfma_f32_16x16x32_bf16(a[0][1], b1, c0, 0, 0, 0);
      c1 = __builtin_amdgcn_mfma_f32_16x16x32_bf16(a[1][0], b0, c1, 0, 0, 0);
      c1 = __builtin_amdgcn_mfma_f32_16x16x32_bf16(a[1][1], b1, c1, 0, 0, 0);
      int base = floc * TSF + k0 + lr;
      #pragma unroll
      for (int reg = 0; reg < 4; ++reg) {
        Ts[(lg * 4 + reg) * TSN + base] = f2bf(c0[reg]);
        Ts[(16 + lg * 4 + reg) * TSN + base] = f2bf(c1[reg]);
      }
    }
    __syncthreads();
    // ---- consumer: wave w applies its 8 nodes' edges.
    #pragma unroll
    for (int i = 0; i < 8; ++i) {
      int deg = deg8[i];
      if (deg == 0) continue;
      int nl = w * 8 + i;
      short8 bt = *(const short8*)(&Ts[nl * TSN + lr * TSF + lg * 8]);
      for (int p = 0; p * 16 < deg; ++p) {
        int ev = 0, dv = 0;
        if (lane < 16 && p * 16 + lane < deg) {
          ev = eord[beg8[i] + p * 16 + lane];
          dv = ei[EE + ev];
        }
        int el = __shfl(ev, lr);
        short8 au = *(const short8*)(ubf + (size_t)el * HH + kq * 32 + lg * 8);
        if (p == 0) {
          acc0[i] = __builtin_amdgcn_mfma_f32_16x16x32_bf16(au, bt, acc0[i],
                                                            0, 0, 0);
          if (kq == 3) {
            #pragma unroll
            for (int reg = 0; reg < 4; ++reg) {
              int eidx = lg * 4 + reg;
              if (eidx < deg) {
                int dstn = __shfl(dv, eidx);
                atomicAdd(&agg[(size_t)dstn * DD + by * 16 + lr],
                          acc0[i][reg] + ccs[nl][lr]);
              }
            }
          }
        } else {
          f32x4 tv = {};
          tv = __builtin_amdgcn_mfma_f32_16x16x32_bf16(au, bt, tv, 0, 0, 0);
          float cadd = (kq == 3) ? ccs[nl][lr] : 0.f;
          #pragma unroll
          for (int reg = 0; reg < 4; ++reg) {
            int eidx = p * 16 + lg * 4 + reg;
            if (eidx < deg) {
              int dstn = __shfl(dv, lg * 4 + reg);
              atomicAdd(&agg[(size_t)dstn * DD + by * 16 + lr], tv[reg] + cadd);
            }
          }
        }
      }
    }
  }
}

// out = x + agg/max(cnt,1) + h@root + bias
__global__ __launch_bounds__(256) void k_final(const float* __restrict__ x,
    const float* __restrict__ h, const float* __restrict__ root,
    const float* __restrict__ bias, const float* __restrict__ agg,
    const int* __restrict__ cnt, float* __restrict__ out) {
  __shared__ float Bs[DD][DD + 1];
  __shared__ float As[32][DD];
  int t = threadIdx.x;
  #pragma unroll
  for (int i = 0; i < 16; ++i) {
    int idx = t + i * 256;
    Bs[idx >> 6][idx & 63] = root[idx];
  }
  int row0 = blockIdx.x * 32;
  #pragma unroll
  for (int i = 0; i < 8; ++i) {
    int idx = t + i * 256;
    int r = idx >> 6, d = idx & 63;
    int gr = row0 + r;
    As[r][d] = (gr < NS) ? h[gr * DD + d] : 0.f;
  }
  __syncthreads();
  int r = t >> 3;
  int c0 = (t & 7) * 8;
  int gr = row0 + r;
  if (gr >= NS) return;
  float acc[8] = {};
  for (int d = 0; d < DD; ++d) {
    float a = As[r][d];
    #pragma unroll
    for (int j = 0; j < 8; ++j) acc[j] += a * Bs[d][c0 + j];
  }
  float inv = 1.0f / fmaxf((float)cnt[gr], 1.0f);
  #pragma unroll
  for (int j = 0; j < 8; ++j) {
    size_t gi = (size_t)gr * DD + c0 + j;
    out[gi] = x[gi] + agg[gi] * inv + acc[j] + bias[c0 + j];
  }
}

extern "C" void kernel_launch(void* const* d_in, const int* in_sizes, int n_in,
                              void* d_out, int out_size, void* d_ws, size_t ws_size,
                              hipStream_t stream) {
  const float* x     = (const float*)d_in[0];
  const float* ea    = (const float*)d_in[1];
  const float* gamma = (const float*)d_in[2];
  const float* beta  = (const float*)d_in[3];
  const float* w1    = (const float*)d_in[4];
  const float* b1    = (const float*)d_in[5];
  const float* w2    = (const float*)d_in[6];
  const float* b2    = (const float*)d_in[7];
  const float* root  = (const float*)d_in[8];
  const float* bias  = (const float*)d_in[9];
  const int*   ei    = (const int*)d_in[10];
  float* out = (float*)d_out;

  char* p = (char*)d_ws;
  auto carve = [&](size_t bytes) {
    char* q = p;
    p += (bytes + 255) & ~(size_t)255;
    return q;
  };
  float* h             = (float*)carve(sizeof(float) * NS * DD);
  unsigned short* hbf  = (unsigned short*)carve(sizeof(short) * NS * DD);
  float* cc            = (float*)carve(sizeof(float) * NS * DD);
  unsigned short* w2t2 = (unsigned short*)carve(sizeof(short) * HH * DD * DD);
  unsigned short* eabf = (unsigned short*)carve(sizeof(short) * (size_t)EE * DD);
  unsigned short* ubf  = (unsigned short*)carve(sizeof(short) * (size_t)EE * HH);
  int* rowptr          = (int*)carve(sizeof(int) * (NS + 1));
  int* cursor          = (int*)carve(sizeof(int) * NS);
  int* eord            = (int*)carve(sizeof(int) * EE);
  // contiguous zero-region: agg | cntdst | cntsrc (single memset)
  char* z0 = p;
  float* agg           = (float*)carve(sizeof(float) * NS * DD);
  int* cntdst          = (int*)carve(sizeof(int) * NS);
  int* cntsrc          = (int*)carve(sizeof(int) * NS);
  size_t zlen = (size_t)(p - z0);

  hipMemsetAsync(z0, 0, zlen, stream);

  k_prep<<<dim3((NS + 3) / 4), dim3(256), 0, stream>>>(
      x, gamma, beta, h, hbf, ea, eabf, w2, w2t2, ei, cntsrc, cntdst);
  k_mid<<<dim3(UBLK + GBLK + 1), dim3(256), 0, stream>>>(
      eabf, w1, b1, ubf, h, b2, cc, cntsrc, rowptr, cursor);
  k_scatter<<<dim3((EE + 255) / 256), dim3(256), 0, stream>>>(ei, cursor, eord);
  k_fused3<<<dim3((NS + 31) / 32, 4), dim3(256), 0, stream>>>(
      hbf, w2t2, ubf, cc, ei, rowptr, eord, agg);
  k_final<<<dim3((NS + 31) / 32), dim3(256), 0, stream>>>(x, h, root, bias, agg,
                                                          cntdst, out);
}

// Round 9
// 158.019 us; speedup vs baseline: 1.9932x; 1.2072x over previous
//
#include <hip/hip_runtime.h>

#define NS 10000
#define DD 64
#define HH 128
#define EE 50000
#define SLOPE 0.01f

typedef __attribute__((ext_vector_type(8))) short short8;
typedef __attribute__((ext_vector_type(4))) float f32x4;

static __device__ __forceinline__ unsigned short f2bf(float f) {
  unsigned int u = __float_as_uint(f);
  u += 0x7fff + ((u >> 16) & 1);   // round-to-nearest-even
  return (unsigned short)(u >> 16);
}

__device__ __forceinline__ float wave_sum64(float v) {
  #pragma unroll
  for (int m = 32; m >= 1; m >>= 1) v += __shfl_xor(v, m, 64);
  return v;
}

// h = leaky(LN(x)) (+bf16), degree counts, ea->bf16, w2->w2t2, w1->w1t, b2->b2t.
__global__ __launch_bounds__(256) void k_prep(const float* __restrict__ x,
    const float* __restrict__ gamma, const float* __restrict__ beta,
    float* __restrict__ h, unsigned short* __restrict__ hbf,
    const float* __restrict__ ea, unsigned short* __restrict__ eabf,
    const float* __restrict__ w2, unsigned short* __restrict__ w2t2,
    const float* __restrict__ w1, unsigned short* __restrict__ w1t,
    const float* __restrict__ b2, unsigned short* __restrict__ b2t,
    const int* __restrict__ ei, int* __restrict__ cntsrc,
    int* __restrict__ cntdst) {
  int gid = blockIdx.x * 256 + threadIdx.x;
  if (gid < EE) {
    atomicAdd(&cntsrc[ei[gid]], 1);
    atomicAdd(&cntdst[ei[EE + gid]], 1);
  }
  if (gid < EE * DD / 8) {
    const float4* sp = (const float4*)(ea + (size_t)gid * 8);
    float4 v0 = sp[0], v1 = sp[1];
    short8 o;
    o[0] = f2bf(v0.x); o[1] = f2bf(v0.y); o[2] = f2bf(v0.z); o[3] = f2bf(v0.w);
    o[4] = f2bf(v1.x); o[5] = f2bf(v1.y); o[6] = f2bf(v1.z); o[7] = f2bf(v1.w);
    *(short8*)(eabf + (size_t)gid * 8) = o;
  }
  if (gid < HH * DD * DD) {
    int d = gid & 63;
    int c2 = gid >> 6;
    int f = c2 >> 7, k = c2 & 127;
    w2t2[gid] = f2bf(w2[k * (DD * DD) + d * DD + f]);
  }
  if (gid < DD * HH) {   // w1t[hc*64+d] = w1[d*128+hc]
    int d = gid & 63, hc = gid >> 6;
    w1t[gid] = f2bf(w1[d * HH + hc]);
  }
  if (gid < DD * DD) {   // b2t[f*64+d] = b2[d*64+f]
    int d = gid & 63, f = gid >> 6;
    b2t[gid] = f2bf(b2[d * DD + f]);
  }
  int wid = threadIdx.x >> 6;
  int lane = threadIdx.x & 63;
  int row = blockIdx.x * 4 + wid;
  if (row >= NS) return;
  float v = x[row * DD + lane];
  float s = wave_sum64(v);
  float s2 = wave_sum64(v * v);
  float mu = s * (1.0f / 64.0f);
  float var = s2 * (1.0f / 64.0f) - mu * mu;
  float r = rsqrtf(var + 1e-5f);
  float hn = (v - mu) * r * gamma[lane] + beta[lane];
  float hv = hn >= 0.f ? hn : SLOPE * hn;
  h[row * DD + lane] = hv;
  hbf[row * DD + lane] = f2bf(hv);
}

// exclusive scan of cntsrc -> rowptr[N+1], cursor. 1024 threads, CH=10.
__global__ __launch_bounds__(1024) void k_scan(const int* __restrict__ cntsrc,
    int* __restrict__ rowptr, int* __restrict__ cursor) {
  __shared__ int ps[1024];
  int t = threadIdx.x;
  const int CH = (NS + 1023) / 1024;
  int base = t * CH;
  int sum = 0;
  for (int i = 0; i < CH; ++i) {
    int idx = base + i;
    if (idx < NS) sum += cntsrc[idx];
  }
  ps[t] = sum;
  __syncthreads();
  for (int off = 1; off < 1024; off <<= 1) {
    int v = (t >= off) ? ps[t - off] : 0;
    __syncthreads();
    ps[t] += v;
    __syncthreads();
  }
  int run = ps[t] - sum;
  for (int i = 0; i < CH; ++i) {
    int idx = base + i;
    if (idx < NS) {
      rowptr[idx] = run;
      cursor[idx] = run;
      run += cntsrc[idx];
    }
  }
  if (t == 1023) rowptr[NS] = run;
}

// staging-free MFMA: blocks [0,UBLK): ubf = bf16(leaky(eabf@w1+b1));
// blocks [UBLK, UBLK+CBLK): cc = h@b2 (f32 out). No LDS, no barriers.
#define UBLK 782
#define CBLK 157
__global__ __launch_bounds__(256) void k_mid(
    const unsigned short* __restrict__ eabf, const unsigned short* __restrict__ w1t,
    const float* __restrict__ b1, unsigned short* __restrict__ ubf,
    const unsigned short* __restrict__ hbf, const unsigned short* __restrict__ b2t,
    float* __restrict__ cc) {
  int t = threadIdx.x;
  int bid = blockIdx.x;
  int w = t >> 6, lane = t & 63, lr = lane & 15, lg = lane >> 4;
  if (bid < UBLK) {
    int r0 = bid * 64 + w * 16;
    int ra = r0 + lr; if (ra >= EE) ra = EE - 1;
    short8 a0 = *(const short8*)(eabf + (size_t)ra * DD + lg * 8);
    short8 a1 = *(const short8*)(eabf + (size_t)ra * DD + 32 + lg * 8);
    f32x4 acc[8] = {};
    #pragma unroll
    for (int ni = 0; ni < 8; ++ni) {
      const unsigned short* bp = w1t + (ni * 16 + lr) * DD;
      short8 b0 = *(const short8*)(bp + lg * 8);
      short8 b1v = *(const short8*)(bp + 32 + lg * 8);
      acc[ni] = __builtin_amdgcn_mfma_f32_16x16x32_bf16(a0, b0, acc[ni], 0, 0, 0);
      acc[ni] = __builtin_amdgcn_mfma_f32_16x16x32_bf16(a1, b1v, acc[ni], 0, 0, 0);
    }
    #pragma unroll
    for (int ni = 0; ni < 8; ++ni) {
      int col = ni * 16 + lr;
      float bb = b1[col];
      #pragma unroll
      for (int reg = 0; reg < 4; ++reg) {
        int gr = r0 + lg * 4 + reg;
        if (gr < EE) {
          float vv = acc[ni][reg] + bb;
          ubf[(size_t)gr * HH + col] = f2bf(vv >= 0.f ? vv : SLOPE * vv);
        }
      }
    }
  } else {
    int row0 = (bid - UBLK) * 64;
    short8 a[4][2];
    #pragma unroll
    for (int mi = 0; mi < 4; ++mi) {
      int ra = row0 + mi * 16 + lr; if (ra >= NS) ra = NS - 1;
      a[mi][0] = *(const short8*)(hbf + (size_t)ra * DD + lg * 8);
      a[mi][1] = *(const short8*)(hbf + (size_t)ra * DD + 32 + lg * 8);
    }
    const unsigned short* bp = b2t + (w * 16 + lr) * DD;
    short8 b0 = *(const short8*)(bp + lg * 8);
    short8 b1v = *(const short8*)(bp + 32 + lg * 8);
    f32x4 acc[4] = {};
    #pragma unroll
    for (int mi = 0; mi < 4; ++mi) {
      acc[mi] = __builtin_amdgcn_mfma_f32_16x16x32_bf16(a[mi][0], b0, acc[mi], 0, 0, 0);
      acc[mi] = __builtin_amdgcn_mfma_f32_16x16x32_bf16(a[mi][1], b1v, acc[mi], 0, 0, 0);
    }
    #pragma unroll
    for (int mi = 0; mi < 4; ++mi)
      #pragma unroll
      for (int reg = 0; reg < 4; ++reg) {
        int gr = row0 + mi * 16 + lg * 4 + reg;
        if (gr < NS) cc[(size_t)gr * DD + w * 16 + lr] = acc[mi][reg];
      }
  }
}

__global__ __launch_bounds__(256) void k_scatter(const int* __restrict__ ei,
    int* __restrict__ cursor, int* __restrict__ eord) {
  int e = blockIdx.x * 256 + threadIdx.x;
  if (e < EE) {
    int s = ei[e];
    int pos = atomicAdd(&cursor[s], 1);
    eord[pos] = e;
  }
}

// T GEMM, staging-free: A/B fragments direct from L2 (no reuse within block),
// LDS only for the store-transpose. One barrier. Tile 64 rows x 256 c2-cols.
__global__ __launch_bounds__(256) void k_T_mfma(
    const unsigned short* __restrict__ hbf, const unsigned short* __restrict__ w2t2,
    unsigned short* __restrict__ T, int n0, int n1) {
  __shared__ unsigned short Ts[64 * 264];
  int t = threadIdx.x;
  int w = t >> 6, lane = t & 63, lr = lane & 15, lg = lane >> 4;
  int row0 = n0 + blockIdx.x * 64;
  int col0 = blockIdx.y * 256;
  short8 a[4][2];
  #pragma unroll
  for (int mi = 0; mi < 4; ++mi) {
    int ra = row0 + mi * 16 + lr; if (ra >= n1) ra = n1 - 1;
    a[mi][0] = *(const short8*)(hbf + (size_t)ra * DD + lg * 8);
    a[mi][1] = *(const short8*)(hbf + (size_t)ra * DD + 32 + lg * 8);
  }
  f32x4 acc[4][4] = {};
  #pragma unroll
  for (int ni = 0; ni < 4; ++ni) {
    int gc = col0 + w * 64 + ni * 16 + lr;
    const unsigned short* bp = w2t2 + (size_t)gc * DD;
    short8 b0 = *(const short8*)(bp + lg * 8);
    short8 b1 = *(const short8*)(bp + 32 + lg * 8);
    #pragma unroll
    for (int mi = 0; mi < 4; ++mi) {
      acc[mi][ni] = __builtin_amdgcn_mfma_f32_16x16x32_bf16(
          a[mi][0], b0, acc[mi][ni], 0, 0, 0);
      acc[mi][ni] = __builtin_amdgcn_mfma_f32_16x16x32_bf16(
          a[mi][1], b1, acc[mi][ni], 0, 0, 0);
    }
  }
  #pragma unroll
  for (int mi = 0; mi < 4; ++mi)
    #pragma unroll
    for (int ni = 0; ni < 4; ++ni) {
      int col = w * 64 + ni * 16 + lr;
      #pragma unroll
      for (int reg = 0; reg < 4; ++reg)
        Ts[(mi * 16 + lg * 4 + reg) * 264 + col] = f2bf(acc[mi][ni][reg]);
    }
  __syncthreads();
  #pragma unroll
  for (int i = 0; i < 8; ++i) {
    int idx = t + i * 256;           // 0..2047
    int row = idx >> 5, seg = idx & 31;
    int gr = row0 + row;
    if (gr < n1) {
      short8 v = *(const short8*)(&Ts[row * 264 + seg * 8]);
      *(short8*)(T + (size_t)(gr - n0) * (HH * DD) + col0 + seg * 8) = v;
    }
  }
}

// Wave-per-node message pass; first-pass edge loads hoisted above T loads.
__global__ __launch_bounds__(256) void k_msg_wave(
    const unsigned short* __restrict__ ubf, const unsigned short* __restrict__ T,
    const float* __restrict__ cc, const int* __restrict__ ei,
    const int* __restrict__ rowptr, const int* __restrict__ eord,
    float* __restrict__ agg, int n0, int n1) {
  int wid = threadIdx.x >> 6;
  int lane = threadIdx.x & 63;
  int s = n0 + blockIdx.x * 4 + wid;
  if (s >= n1) return;
  int beg = rowptr[s];
  int deg = rowptr[s + 1] - beg;
  if (deg == 0) return;
  int lr = lane & 15, lg = lane >> 4;
  int ev = 0, dv = 0;
  if (lane < 16 && lane < deg) {     // hoisted: overlaps with T loads below
    ev = eord[beg + lane];
    dv = ei[EE + ev];
  }
  const unsigned short* tp = T + (size_t)(s - n0) * (HH * DD);
  short8 b[4][4];   // [ftile][kstep]
  #pragma unroll
  for (int ft = 0; ft < 4; ++ft)
    #pragma unroll
    for (int kk = 0; kk < 4; ++kk)
      b[ft][kk] =
          *(const short8*)(tp + (ft * 16 + lr) * HH + kk * 32 + lg * 8);
  float clv[4];
  #pragma unroll
  for (int ft = 0; ft < 4; ++ft) clv[ft] = cc[(size_t)s * DD + ft * 16 + lr];

  for (int p0 = 0; p0 < deg; p0 += 16) {
    if (p0) {
      ev = 0; dv = 0;
      if (lane < 16 && p0 + lane < deg) {
        ev = eord[beg + p0 + lane];
        dv = ei[EE + ev];
      }
    }
    int el = __shfl(ev, (p0 + lr < deg) ? lr : 0);
    const unsigned short* up = ubf + (size_t)el * HH;
    short8 au[4];
    #pragma unroll
    for (int kk = 0; kk < 4; ++kk)
      au[kk] = *(const short8*)(up + kk * 32 + lg * 8);
    f32x4 acc[4] = {};
    #pragma unroll
    for (int kk = 0; kk < 4; ++kk)
      #pragma unroll
      for (int ft = 0; ft < 4; ++ft)
        acc[ft] = __builtin_amdgcn_mfma_f32_16x16x32_bf16(au[kk], b[ft][kk],
                                                          acc[ft], 0, 0, 0);
    #pragma unroll
    for (int reg = 0; reg < 4; ++reg) {
      int eidx = p0 + lg * 4 + reg;
      int dstn = __shfl(dv, lg * 4 + reg);
      if (eidx < deg) {
        #pragma unroll
        for (int ft = 0; ft < 4; ++ft)
          atomicAdd(&agg[(size_t)dstn * DD + ft * 16 + lr],
                    acc[ft][reg] + clv[ft]);
      }
    }
  }
}

// out = x + agg/max(cnt,1) + h@root + bias
__global__ __launch_bounds__(256) void k_final(const float* __restrict__ x,
    const float* __restrict__ h, const float* __restrict__ root,
    const float* __restrict__ bias, const float* __restrict__ agg,
    const int* __restrict__ cnt, float* __restrict__ out) {
  __shared__ float Bs[DD][DD + 1];
  __shared__ float As[32][DD];
  int t = threadIdx.x;
  #pragma unroll
  for (int i = 0; i < 16; ++i) {
    int idx = t + i * 256;
    Bs[idx >> 6][idx & 63] = root[idx];
  }
  int row0 = blockIdx.x * 32;
  #pragma unroll
  for (int i = 0; i < 8; ++i) {
    int idx = t + i * 256;
    int r = idx >> 6, d = idx & 63;
    int gr = row0 + r;
    As[r][d] = (gr < NS) ? h[gr * DD + d] : 0.f;
  }
  __syncthreads();
  int r = t >> 3;
  int c0 = (t & 7) * 8;
  int gr = row0 + r;
  if (gr >= NS) return;
  float acc[8] = {};
  for (int d = 0; d < DD; ++d) {
    float a = As[r][d];
    #pragma unroll
    for (int j = 0; j < 8; ++j) acc[j] += a * Bs[d][c0 + j];
  }
  float inv = 1.0f / fmaxf((float)cnt[gr], 1.0f);
  #pragma unroll
  for (int j = 0; j < 8; ++j) {
    size_t gi = (size_t)gr * DD + c0 + j;
    out[gi] = x[gi] + agg[gi] * inv + acc[j] + bias[c0 + j];
  }
}

extern "C" void kernel_launch(void* const* d_in, const int* in_sizes, int n_in,
                              void* d_out, int out_size, void* d_ws, size_t ws_size,
                              hipStream_t stream) {
  const float* x     = (const float*)d_in[0];
  const float* ea    = (const float*)d_in[1];
  const float* gamma = (const float*)d_in[2];
  const float* beta  = (const float*)d_in[3];
  const float* w1    = (const float*)d_in[4];
  const float* b1    = (const float*)d_in[5];
  const float* w2    = (const float*)d_in[6];
  const float* b2    = (const float*)d_in[7];
  const float* root  = (const float*)d_in[8];
  const float* bias  = (const float*)d_in[9];
  const int*   ei    = (const int*)d_in[10];
  float* out = (float*)d_out;

  char* p = (char*)d_ws;
  auto carve = [&](size_t bytes) {
    char* q = p;
    p += (bytes + 255) & ~(size_t)255;
    return q;
  };
  float* h             = (float*)carve(sizeof(float) * NS * DD);
  unsigned short* hbf  = (unsigned short*)carve(sizeof(short) * NS * DD);
  float* cc            = (float*)carve(sizeof(float) * NS * DD);
  unsigned short* w2t2 = (unsigned short*)carve(sizeof(short) * HH * DD * DD);
  unsigned short* w1t  = (unsigned short*)carve(sizeof(short) * DD * HH);
  unsigned short* b2t  = (unsigned short*)carve(sizeof(short) * DD * DD);
  unsigned short* eabf = (unsigned short*)carve(sizeof(short) * (size_t)EE * DD);
  unsigned short* ubf  = (unsigned short*)carve(sizeof(short) * (size_t)EE * HH);
  int* rowptr          = (int*)carve(sizeof(int) * (NS + 1));
  int* cursor          = (int*)carve(sizeof(int) * NS);
  int* eord            = (int*)carve(sizeof(int) * EE);
  // contiguous zero-region: agg | cntdst | cntsrc (single memset)
  char* z0 = p;
  float* agg           = (float*)carve(sizeof(float) * NS * DD);
  int* cntdst          = (int*)carve(sizeof(int) * NS);
  int* cntsrc          = (int*)carve(sizeof(int) * NS);
  size_t zlen = (size_t)(p - z0);
  size_t fixed = (size_t)(p - (char*)d_ws);

  size_t freeb = (ws_size > fixed) ? (ws_size - fixed - 256) : 0;
  int rows = (int)(freeb / (sizeof(short) * HH * DD));
  if (rows > NS) rows = NS;
  rows &= ~63;
  if (rows < 64) rows = 64;
  unsigned short* Tt = (unsigned short*)carve(sizeof(short) * (size_t)rows * HH * DD);

  hipMemsetAsync(z0, 0, zlen, stream);

  k_prep<<<dim3((NS + 3) / 4), dim3(256), 0, stream>>>(
      x, gamma, beta, h, hbf, ea, eabf, w2, w2t2, w1, w1t, b2, b2t,
      ei, cntsrc, cntdst);
  k_scan<<<dim3(1), dim3(1024), 0, stream>>>(cntsrc, rowptr, cursor);
  k_mid<<<dim3(UBLK + CBLK), dim3(256), 0, stream>>>(
      eabf, w1t, b1, ubf, hbf, b2t, cc);
  k_scatter<<<dim3((EE + 255) / 256), dim3(256), 0, stream>>>(ei, cursor, eord);

  for (int n0 = 0; n0 < NS; n0 += rows) {
    int n1 = n0 + rows;
    if (n1 > NS) n1 = NS;
    int nr = n1 - n0;
    k_T_mfma<<<dim3((nr + 63) / 64, (HH * DD) / 256), dim3(256), 0, stream>>>(
        hbf, w2t2, Tt, n0, n1);
    k_msg_wave<<<dim3((nr + 3) / 4), dim3(256), 0, stream>>>(
        ubf, Tt, cc, ei, rowptr, eord, agg, n0, n1);
  }

  k_final<<<dim3((NS + 31) / 32), dim3(256), 0, stream>>>(x, h, root, bias, agg,
                                                          cntdst, out);
}